// Round 4
// baseline (848.760 us; speedup 1.0000x reference)
//
#include <hip/hip_runtime.h>
#include <hip/hip_bf16.h>

#define S_LEN 2048
#define NB 2
#define NH 16
#define DH 128
#define ROW_STRIDE (NB * NH * DH)           // 4096 floats between consecutive s
#define M_TILE 128
#define N_TILE 64
#define NKT_TOTAL (S_LEN / N_TILE)          // 32
#define PACKED_WORDS (NB * S_LEN * (S_LEN / 64))   // 131072 u64 words
#define NROWS (NB * NH * S_LEN)             // 65536 (b,h,s) rows

// workspace layout (bytes)
#define WS_OP0 0ull
#define WS_OP1 33554432ull
#define WS_L0  67108864ull
#define WS_L1  67371008ull
#define WS_M0  67633152ull
#define WS_M1  67895296ull
#define WS_MP  68157440ull
#define WS_NEED 69206016ull
#define WS_NEED_MP_ONLY (PACKED_WORDS * 8ull)

typedef __bf16 bf16x8_t __attribute__((ext_vector_type(8)));
typedef __bf16 bf16x4_t __attribute__((ext_vector_type(4)));
typedef float  f32x4_t  __attribute__((ext_vector_type(4)));

#define LDS_KS 136
#define LDS_VS 68
#define LDS_PS 68

#if defined(__has_builtin)
#if __has_builtin(__builtin_amdgcn_exp2f)
#define EXP2F __builtin_amdgcn_exp2f
#else
#define EXP2F exp2f
#endif
#else
#define EXP2F exp2f
#endif

// Pack bool mask (int32) into bits: Mp[(b*S+s)*32 + tile] = 64 cols as u64.
__global__ void mask_pack_kernel(const int* __restrict__ Mg,
                                 unsigned long long* __restrict__ Mp) {
    const int lane = threadIdx.x & 63;
    const int wid  = (blockIdx.x * blockDim.x + threadIdx.x) >> 6;
    const int nw   = (gridDim.x * blockDim.x) >> 6;
    for (int g = wid; g < PACKED_WORDS; g += nw) {
        const int row = g >> 5;
        const int cw  = g & 31;
        int v = Mg[(size_t)row * S_LEN + cw * 64 + lane];
        unsigned long long bm = __ballot(v != 0);
        if (lane == 0) Mp[g] = bm;
    }
}

// Combine two split partials into final output.
__global__ __launch_bounds__(256) void combine_kernel(
    const char* __restrict__ ws, float* __restrict__ Og) {
    const float* O0 = (const float*)(ws + WS_OP0);
    const float* O1 = (const float*)(ws + WS_OP1);
    const float* L0 = (const float*)(ws + WS_L0);
    const float* L1 = (const float*)(ws + WS_L1);
    const float* M0 = (const float*)(ws + WS_M0);
    const float* M1 = (const float*)(ws + WS_M1);
    const int gid = blockIdx.x * 256 + threadIdx.x;   // 0 .. NROWS*32
    const int row = gid >> 5;
    const int d0  = (gid & 31) * 4;
    const float m0 = M0[row], m1 = M1[row];
    const float l0 = L0[row], l1 = L1[row];
    const float m  = fmaxf(m0, m1);
    const float a0 = EXP2F(m0 - m), a1 = EXP2F(m1 - m);
    const float inv = 1.0f / (a0 * l0 + a1 * l1);
    float4 o0 = *(const float4*)(O0 + (size_t)row * DH + d0);
    float4 o1 = *(const float4*)(O1 + (size_t)row * DH + d0);
    const int s = row & (S_LEN - 1);
    const int h = (row >> 11) & (NH - 1);
    const int b = row >> 15;
    float4 r;
    r.x = (a0 * o0.x + a1 * o1.x) * inv;
    r.y = (a0 * o0.y + a1 * o1.y) * inv;
    r.z = (a0 * o0.z + a1 * o1.z) * inv;
    r.w = (a0 * o0.w + a1 * o1.w) * inv;
    *(float4*)(Og + (size_t)s * ROW_STRIDE + b * (NH * DH) + h * DH + d0) = r;
}

template <int NSPLIT, bool PACKED>
__global__ __launch_bounds__(256, 4) void fa_kernel(
    const float* __restrict__ Qg, const float* __restrict__ Kg,
    const float* __restrict__ Vg, const int* __restrict__ Mg,
    const uint2* __restrict__ Mp, float* __restrict__ Og,
    char* __restrict__ ws)
{
    // kT (64x136) aliased with pT (4 waves x 32 x 68); vT (128x68) separate.
    __shared__ __bf16 smem[17408];
    __bf16* kT = smem;                 // [t][d], stride 136
    __bf16* vT = smem + 8704;          // [d][t], stride 68

    const int tid  = threadIdx.x;
    const int wave = tid >> 6;
    const int lane = tid & 63;
    const int l15  = lane & 15;
    const int quad = lane >> 4;

    const int bid = blockIdx.x;
    const int qt  = bid & 15;
    const int bh  = (bid >> 4) & 31;
    const int sp  = (NSPLIT == 2) ? (bid >> 9) : 0;
    const int h   = bh & (NH - 1);
    const int b   = bh >> 4;

    const int q0       = qt * M_TILE;
    const int head_off = b * (NH * DH) + h * DH;
    const int kt_base  = sp * (NKT_TOTAL / NSPLIT);
    const int nkt      = NKT_TOTAL / NSPLIT;

    const float kScale   = 1.44269504088896340736f / 11.31370849898476039f;
    const float kMaskVal = -14426.950408889634f;

    // ---- Q fragments, softmax scale folded in ----
    bf16x8_t qf[2][4];
#pragma unroll
    for (int mt = 0; mt < 2; ++mt) {
        const int srow = q0 + wave * 32 + mt * 16 + l15;
        const float* qp = Qg + (size_t)srow * ROW_STRIDE + head_off + quad * 8;
#pragma unroll
        for (int kc = 0; kc < 4; ++kc) {
            float4 f0 = *(const float4*)(qp + kc * 32);
            float4 f1 = *(const float4*)(qp + kc * 32 + 4);
            bf16x8_t v;
            v[0] = (__bf16)(f0.x * kScale); v[1] = (__bf16)(f0.y * kScale);
            v[2] = (__bf16)(f0.z * kScale); v[3] = (__bf16)(f0.w * kScale);
            v[4] = (__bf16)(f1.x * kScale); v[5] = (__bf16)(f1.y * kScale);
            v[6] = (__bf16)(f1.z * kScale); v[7] = (__bf16)(f1.w * kScale);
            qf[mt][kc] = v;
        }
    }

    f32x4_t oacc[2][8];
    float mstate[2][4], lstate[2][4];
#pragma unroll
    for (int mt = 0; mt < 2; ++mt) {
#pragma unroll
        for (int dt = 0; dt < 8; ++dt) oacc[mt][dt] = {0.0f, 0.0f, 0.0f, 0.0f};
#pragma unroll
        for (int r = 0; r < 4; ++r) { mstate[mt][r] = -3.0e38f; lstate[mt][r] = 0.0f; }
    }

    __bf16* pW = smem + wave * (32 * LDS_PS);   // aliases kT region

    for (int kt = 0; kt < nkt; ++kt) {
        const int ktg = kt_base + kt;
        const int t0  = ktg * N_TILE;
        __syncthreads();   // prev tile's pW/vT reads done -> safe to overwrite

        // ---- stage K tile: kT[t][d] ----
        {
            const int r0 = tid >> 5;
            const int c4 = (tid & 31) * 4;
            const float* kp = Kg + (size_t)(t0 + r0) * ROW_STRIDE + head_off + c4;
            __bf16* kd = &kT[r0 * LDS_KS + c4];
#pragma unroll
            for (int rr = 0; rr < 8; ++rr) {
                float4 f = *(const float4*)(kp + (size_t)rr * 8 * ROW_STRIDE);
                bf16x4_t w;
                w[0] = (__bf16)f.x; w[1] = (__bf16)f.y;
                w[2] = (__bf16)f.z; w[3] = (__bf16)f.w;
                *(bf16x4_t*)(kd + rr * 8 * LDS_KS) = w;
            }
        }
        // ---- stage V tile transposed: vT[d][t] ----
        {
            const int tv = tid >> 5;
            const int dv = tid & 31;
            const float* vp = Vg + (size_t)(t0 + tv) * ROW_STRIDE + head_off + dv;
#pragma unroll
            for (int rr = 0; rr < 8; ++rr) {
                const float* vpp = vp + (size_t)rr * 8 * ROW_STRIDE;
                const int trow = tv + rr * 8;
#pragma unroll
                for (int j = 0; j < 4; ++j)
                    vT[(dv + j * 32) * LDS_VS + trow] = (__bf16)vpp[j * 32];
            }
        }
        __syncthreads();

        // ---- mask bits for this tile (L2-resident packed words) ----
        unsigned mpk = 0;
        if (PACKED) {
#pragma unroll
            for (int i = 0; i < 8; ++i) {
                const int mt = i >> 2, r = i & 3;
                const int row = q0 + wave * 32 + mt * 16 + quad * 4 + r;
                uint2 w = Mp[(size_t)(b * S_LEN + row) * 32 + ktg];
                mpk |= (((w.x >> l15) & 1u) | (((w.x >> (l15 + 16)) & 1u) << 1)
                      | (((w.y >> l15) & 1u) << 2) | (((w.y >> (l15 + 16)) & 1u) << 3))
                       << (i * 4);
            }
        } else {
#pragma unroll
            for (int i = 0; i < 8; ++i) {
                const int mt = i >> 2, r = i & 3;
                const int row = q0 + wave * 32 + mt * 16 + quad * 4 + r;
                const int* mp = Mg + (size_t)b * S_LEN * S_LEN + (size_t)row * S_LEN + t0 + l15;
#pragma unroll
                for (int n = 0; n < 4; ++n)
                    mpk |= (mp[n * 16] ? 1u : 0u) << (i * 4 + n);
            }
        }

        // ---- S = Q K^T (reads kT) ----
        f32x4_t sacc[2][4];
#pragma unroll
        for (int mt = 0; mt < 2; ++mt)
#pragma unroll
            for (int n = 0; n < 4; ++n) sacc[mt][n] = {0.0f, 0.0f, 0.0f, 0.0f};
#pragma unroll
        for (int n = 0; n < 4; ++n) {
#pragma unroll
            for (int kc = 0; kc < 4; ++kc) {
                bf16x8_t kb = *(const bf16x8_t*)&kT[(n * 16 + l15) * LDS_KS + kc * 32 + quad * 8];
                sacc[0][n] = __builtin_amdgcn_mfma_f32_16x16x32_bf16(qf[0][kc], kb, sacc[0][n], 0, 0, 0);
                sacc[1][n] = __builtin_amdgcn_mfma_f32_16x16x32_bf16(qf[1][kc], kb, sacc[1][n], 0, 0, 0);
            }
        }
        __syncthreads();   // all waves done reading kT -> safe to write pW (alias)

        // ---- mask + online softmax + P -> pW ----
#pragma unroll
        for (int mt = 0; mt < 2; ++mt) {
            float sv[4][4];
#pragma unroll
            for (int n = 0; n < 4; ++n)
#pragma unroll
                for (int r = 0; r < 4; ++r)
                    sv[n][r] = ((mpk >> ((mt * 4 + r) * 4 + n)) & 1u) ? kMaskVal
                                                                      : sacc[mt][n][r];
#pragma unroll
            for (int r = 0; r < 4; ++r) {
                float tm = fmaxf(fmaxf(sv[0][r], sv[1][r]), fmaxf(sv[2][r], sv[3][r]));
                tm = fmaxf(tm, __shfl_xor(tm, 1, 64));
                tm = fmaxf(tm, __shfl_xor(tm, 2, 64));
                tm = fmaxf(tm, __shfl_xor(tm, 4, 64));
                tm = fmaxf(tm, __shfl_xor(tm, 8, 64));
                const float mold  = mstate[mt][r];
                const float mnew  = fmaxf(mold, tm);
                const float alpha = EXP2F(mold - mnew);
                float rsum = 0.0f;
#pragma unroll
                for (int n = 0; n < 4; ++n) {
                    float p = EXP2F(sv[n][r] - mnew);
                    rsum += p;
                    pW[(mt * 16 + quad * 4 + r) * LDS_PS + n * 16 + l15] = (__bf16)p;
                }
                rsum += __shfl_xor(rsum, 1, 64);
                rsum += __shfl_xor(rsum, 2, 64);
                rsum += __shfl_xor(rsum, 4, 64);
                rsum += __shfl_xor(rsum, 8, 64);
                lstate[mt][r] = lstate[mt][r] * alpha + rsum;
                mstate[mt][r] = mnew;
#pragma unroll
                for (int dt = 0; dt < 8; ++dt) oacc[mt][dt][r] *= alpha;
            }
        }

        // ---- O += P V ----
#pragma unroll
        for (int kc2 = 0; kc2 < 2; ++kc2) {
            bf16x8_t af[2];
#pragma unroll
            for (int mt = 0; mt < 2; ++mt) {
                bf16x4_t lo = *(const bf16x4_t*)&pW[(mt * 16 + l15) * LDS_PS + kc2 * 32 + quad * 8];
                bf16x4_t hi = *(const bf16x4_t*)&pW[(mt * 16 + l15) * LDS_PS + kc2 * 32 + quad * 8 + 4];
                af[mt] = __builtin_shufflevector(lo, hi, 0, 1, 2, 3, 4, 5, 6, 7);
            }
#pragma unroll
            for (int dt = 0; dt < 8; ++dt) {
                bf16x4_t v0 = *(const bf16x4_t*)&vT[(dt * 16 + l15) * LDS_VS + kc2 * 32 + quad * 8];
                bf16x4_t v1 = *(const bf16x4_t*)&vT[(dt * 16 + l15) * LDS_VS + kc2 * 32 + quad * 8 + 4];
                bf16x8_t bfr = __builtin_shufflevector(v0, v1, 0, 1, 2, 3, 4, 5, 6, 7);
                oacc[0][dt] = __builtin_amdgcn_mfma_f32_16x16x32_bf16(af[0], bfr, oacc[0][dt], 0, 0, 0);
                oacc[1][dt] = __builtin_amdgcn_mfma_f32_16x16x32_bf16(af[1], bfr, oacc[1][dt], 0, 0, 0);
            }
        }
    }

    // ---- epilogue ----
    if (NSPLIT == 1) {
#pragma unroll
        for (int mt = 0; mt < 2; ++mt)
#pragma unroll
            for (int r = 0; r < 4; ++r) {
                const float inv = 1.0f / lstate[mt][r];
                const int srow = q0 + wave * 32 + mt * 16 + quad * 4 + r;
                float* op = Og + (size_t)srow * ROW_STRIDE + head_off + l15;
#pragma unroll
                for (int dt = 0; dt < 8; ++dt) op[dt * 16] = oacc[mt][dt][r] * inv;
            }
    } else {
        float* Op = (float*)(ws + (sp ? WS_OP1 : WS_OP0));
        float* Lp = (float*)(ws + (sp ? WS_L1 : WS_L0));
        float* Mq = (float*)(ws + (sp ? WS_M1 : WS_M0));
        const int rowbase = (b * NH + h) * S_LEN;
#pragma unroll
        for (int mt = 0; mt < 2; ++mt)
#pragma unroll
            for (int r = 0; r < 4; ++r) {
                const int srow = q0 + wave * 32 + mt * 16 + quad * 4 + r;
                const int grow = rowbase + srow;
                float* op = Op + (size_t)grow * DH + l15;
#pragma unroll
                for (int dt = 0; dt < 8; ++dt) op[dt * 16] = oacc[mt][dt][r];
                if (l15 == 0) { Lp[grow] = lstate[mt][r]; Mq[grow] = mstate[mt][r]; }
            }
    }
}

extern "C" void kernel_launch(void* const* d_in, const int* in_sizes, int n_in,
                              void* d_out, int out_size, void* d_ws, size_t ws_size,
                              hipStream_t stream) {
    (void)in_sizes; (void)n_in; (void)out_size;
    const float* Q = (const float*)d_in[0];
    const float* K = (const float*)d_in[1];
    const float* V = (const float*)d_in[2];
    const int*   M = (const int*)d_in[3];
    float* O = (float*)d_out;
    dim3 block(256);
    if (d_ws != nullptr && ws_size >= WS_NEED) {
        char* ws = (char*)d_ws;
        unsigned long long* Mp = (unsigned long long*)(ws + WS_MP);
        hipLaunchKernelGGL(mask_pack_kernel, dim3(512), block, 0, stream, M, Mp);
        hipLaunchKernelGGL((fa_kernel<2, true>), dim3(1024), block, 0, stream,
                           Q, K, V, M, (const uint2*)Mp, O, ws);
        hipLaunchKernelGGL(combine_kernel, dim3(NROWS * 32 / 256), block, 0, stream,
                           ws, O);
    } else if (d_ws != nullptr && ws_size >= WS_NEED_MP_ONLY) {
        unsigned long long* Mp = (unsigned long long*)d_ws;
        hipLaunchKernelGGL(mask_pack_kernel, dim3(512), block, 0, stream, M, Mp);
        hipLaunchKernelGGL((fa_kernel<1, true>), dim3(512), block, 0, stream,
                           Q, K, V, M, (const uint2*)Mp, O, (char*)d_ws);
    } else {
        hipLaunchKernelGGL((fa_kernel<1, false>), dim3(512), block, 0, stream,
                           Q, K, V, M, (const uint2*)nullptr, O, (char*)d_ws);
    }
}

// Round 6
// 360.096 us; speedup vs baseline: 2.3570x; 2.3570x over previous
//
#include <hip/hip_runtime.h>
#include <hip/hip_bf16.h>

#define S_LEN 2048
#define NB 2
#define NH 16
#define DH 128
#define ROW_STRIDE (NB * NH * DH)           // 4096 floats between consecutive s
#define NBH (NB * NH)                       // 32
#define N_TILE 64
#define NKT (S_LEN / N_TILE)                // 32
#define PACKED_WORDS (NB * S_LEN * (S_LEN / 64))   // 131072 u64

// workspace layout (bytes)
#define WS_KH 0ull                          // bf16 K, [bh][t][d], 16 MiB
#define WS_VT 16777216ull                   // bf16 V^T, [bh][d][t], 16 MiB
#define WS_MP 33554432ull                   // packed mask, 1 MiB
#define WS_NEED 34603008ull

typedef __bf16 bf16x8_t __attribute__((ext_vector_type(8)));
typedef __bf16 bf16x4_t __attribute__((ext_vector_type(4)));
typedef float  f32x4_t  __attribute__((ext_vector_type(4)));

#define LDS_KS 136   // kT stride (elems)
#define LDS_VS 72    // vT stride (elems, 144B: b128-aligned)
#define LDS_PS 72    // pW stride (aliases kT region)

#if defined(__has_builtin)
#if __has_builtin(__builtin_amdgcn_exp2f)
#define EXP2F __builtin_amdgcn_exp2f
#else
#define EXP2F exp2f
#endif
#else
#define EXP2F exp2f
#endif

// ---------------- pre-pass kernels ----------------

__global__ __launch_bounds__(256) void mask_pack_kernel(
    const int* __restrict__ Mg, unsigned long long* __restrict__ Mp) {
    const int lane = threadIdx.x & 63;
    const int wid  = (blockIdx.x * blockDim.x + threadIdx.x) >> 6;
    const int nw   = (gridDim.x * blockDim.x) >> 6;
    for (int g = wid; g < PACKED_WORDS; g += nw) {
        const int row = g >> 5;
        const int cw  = g & 31;
        int v = Mg[(size_t)row * S_LEN + cw * 64 + lane];
        unsigned long long bm = __ballot(v != 0);
        if (lane == 0) Mp[g] = bm;
    }
}

// K fp32 [t][b][h][d] -> bf16 [bh][t][d]   (8.39M elems / 8 per thread = 4096 blocks)
__global__ __launch_bounds__(256) void convert_k_kernel(
    const float* __restrict__ Kg, __bf16* __restrict__ Kh) {
    const size_t o = ((size_t)blockIdx.x * 256 + threadIdx.x) * 8;
    const int d  = (int)(o & 127);
    const int t  = (int)((o >> 7) & 2047);
    const int bh = (int)(o >> 18);
    const int b = bh >> 4, h = bh & 15;
    const float* ip = Kg + (size_t)t * ROW_STRIDE + b * (NH * DH) + h * DH + d;
    float4 f0 = *(const float4*)ip;
    float4 f1 = *(const float4*)(ip + 4);
    bf16x8_t v;
    v[0] = (__bf16)f0.x; v[1] = (__bf16)f0.y; v[2] = (__bf16)f0.z; v[3] = (__bf16)f0.w;
    v[4] = (__bf16)f1.x; v[5] = (__bf16)f1.y; v[6] = (__bf16)f1.z; v[7] = (__bf16)f1.w;
    *(bf16x8_t*)(Kh + o) = v;
}

// V fp32 [t][b][h][d] -> bf16 transposed [bh][d][t]
__global__ __launch_bounds__(256) void transpose_v_kernel(
    const float* __restrict__ Vg, __bf16* __restrict__ Vt) {
    __shared__ __bf16 vS[DH * 68];
    const int tid = threadIdx.x;
    const int bh  = blockIdx.x >> 5;
    const int tc  = blockIdx.x & 31;
    const int t0  = tc * 64;
    const int b = bh >> 4, h = bh & 15;
    const int head_off = b * (NH * DH) + h * DH;
    const int tv = tid >> 5;
    const int dv = tid & 31;
    const float* vp = Vg + (size_t)(t0 + tv) * ROW_STRIDE + head_off + dv;
#pragma unroll
    for (int rr = 0; rr < 8; ++rr) {
        const float* vpp = vp + (size_t)rr * 8 * ROW_STRIDE;
        const int trow = tv + rr * 8;
#pragma unroll
        for (int j = 0; j < 4; ++j)
            vS[(dv + j * 32) * 68 + trow] = (__bf16)vpp[j * 32];
    }
    __syncthreads();
    const int d    = tid >> 1;
    const int half = (tid & 1) * 32;
    __bf16* op = Vt + ((size_t)bh * DH + d) * S_LEN + t0 + half;
#pragma unroll
    for (int k = 0; k < 4; ++k) {
        bf16x4_t lo = *(const bf16x4_t*)&vS[d * 68 + half + k * 8];
        bf16x4_t hi = *(const bf16x4_t*)&vS[d * 68 + half + k * 8 + 4];
        bf16x8_t w = __builtin_shufflevector(lo, hi, 0, 1, 2, 3, 4, 5, 6, 7);
        *(bf16x8_t*)(op + k * 8) = w;
    }
}

// ---------------- main attention kernel (M_TILE = 64) ----------------

__global__ __launch_bounds__(256, 3) void fa_main(
    const float* __restrict__ Qg, const __bf16* __restrict__ Kh,
    const __bf16* __restrict__ Vt, const uint2* __restrict__ Mp,
    float* __restrict__ Og)
{
    // kT (64 x 136, aliased with per-wave pW) + vT (128 x 72)
    __shared__ __bf16 smem[64 * LDS_KS + DH * LDS_VS];   // 17920 elems = 35840 B
    __bf16* kT = smem;
    __bf16* vT = smem + 64 * LDS_KS;

    const int tid  = threadIdx.x;
    const int wave = tid >> 6;
    const int lane = tid & 63;
    const int l15  = lane & 15;
    const int quad = lane >> 4;

    const int bid = blockIdx.x;
    const int qt  = bid & 31;            // 32 q-tiles of 64 rows
    const int bh  = bid >> 5;
    const int h   = bh & (NH - 1);
    const int b   = bh >> 4;

    const int q0       = qt * 64;
    const int head_off = b * (NH * DH) + h * DH;

    const float kScale   = 1.44269504088896340736f / 11.31370849898476039f;
    const float kMaskVal = -14426.950408889634f;

    const __bf16* khp = Kh + (size_t)bh * S_LEN * DH;
    const __bf16* vtp = Vt + (size_t)bh * DH * S_LEN;

    // staging coords
    const int krow = tid >> 2;           // 0..63
    const int kcol = (tid & 3) * 32;     // 64B chunks
    const int vrow = tid >> 1;           // 0..127
    const int vhalf = (tid & 1) * 32;

    // ---- Q fragments (A-layout), scale folded ----
    bf16x8_t qf[4];
    {
        const int srow = q0 + wave * 16 + l15;
        const float* qp = Qg + (size_t)srow * ROW_STRIDE + head_off + quad * 8;
#pragma unroll
        for (int kc = 0; kc < 4; ++kc) {
            float4 f0 = *(const float4*)(qp + kc * 32);
            float4 f1 = *(const float4*)(qp + kc * 32 + 4);
            bf16x8_t v;
            v[0] = (__bf16)(f0.x * kScale); v[1] = (__bf16)(f0.y * kScale);
            v[2] = (__bf16)(f0.z * kScale); v[3] = (__bf16)(f0.w * kScale);
            v[4] = (__bf16)(f1.x * kScale); v[5] = (__bf16)(f1.y * kScale);
            v[6] = (__bf16)(f1.z * kScale); v[7] = (__bf16)(f1.w * kScale);
            qf[kc] = v;
        }
    }

    f32x4_t oacc[8];
    float mstate[4], lstate[4];
#pragma unroll
    for (int dt = 0; dt < 8; ++dt) oacc[dt] = {0.0f, 0.0f, 0.0f, 0.0f};
#pragma unroll
    for (int r = 0; r < 4; ++r) { mstate[r] = -3.0e38f; lstate[r] = 0.0f; }

    __bf16* pW = smem + wave * (16 * LDS_PS);   // aliases kT region (4*16*72 <= 64*136)

    for (int kt = 0; kt < NKT; ++kt) {
        const int t0 = kt * N_TILE;

        // ---- issue this tile's global loads (regs only; overlaps prev PV + barrier) ----
        bf16x8_t kldg[4], vldg[4];
        {
            const __bf16* kp = khp + (size_t)(t0 + krow) * DH + kcol;
#pragma unroll
            for (int k = 0; k < 4; ++k) kldg[k] = *(const bf16x8_t*)(kp + k * 8);
            const __bf16* vp = vtp + (size_t)vrow * S_LEN + t0 + vhalf;
#pragma unroll
            for (int k = 0; k < 4; ++k) vldg[k] = *(const bf16x8_t*)(vp + k * 8);
        }
        unsigned mpk = 0;
#pragma unroll
        for (int r = 0; r < 4; ++r) {
            const int row = q0 + wave * 16 + quad * 4 + r;
            uint2 w = Mp[(size_t)(b * S_LEN + row) * 32 + kt];
            mpk |= (((w.x >> l15) & 1u) | (((w.x >> (l15 + 16)) & 1u) << 1)
                  | (((w.y >> l15) & 1u) << 2) | (((w.y >> (l15 + 16)) & 1u) << 3))
                   << (r * 4);
        }

        __syncthreads();   // prev tile's pW/vT readers done

        // ---- regs -> LDS ----
#pragma unroll
        for (int k = 0; k < 4; ++k)
            *(bf16x8_t*)(kT + krow * LDS_KS + kcol + k * 8) = kldg[k];
#pragma unroll
        for (int k = 0; k < 4; ++k)
            *(bf16x8_t*)(vT + vrow * LDS_VS + vhalf + k * 8) = vldg[k];
        __syncthreads();

        // ---- S = Q K^T ----
        f32x4_t sacc[4];
#pragma unroll
        for (int n = 0; n < 4; ++n) sacc[n] = {0.0f, 0.0f, 0.0f, 0.0f};
#pragma unroll
        for (int n = 0; n < 4; ++n)
#pragma unroll
            for (int kc = 0; kc < 4; ++kc) {
                bf16x8_t kb = *(const bf16x8_t*)&kT[(n * 16 + l15) * LDS_KS + kc * 32 + quad * 8];
                sacc[n] = __builtin_amdgcn_mfma_f32_16x16x32_bf16(qf[kc], kb, sacc[n], 0, 0, 0);
            }
        __syncthreads();   // kT readers done -> pW (alias) writable

        // ---- mask + online softmax, P -> pW ----
        {
            float sv[4][4];
#pragma unroll
            for (int n = 0; n < 4; ++n)
#pragma unroll
                for (int r = 0; r < 4; ++r)
                    sv[n][r] = ((mpk >> (r * 4 + n)) & 1u) ? kMaskVal : sacc[n][r];
#pragma unroll
            for (int r = 0; r < 4; ++r) {
                float tm = fmaxf(fmaxf(sv[0][r], sv[1][r]), fmaxf(sv[2][r], sv[3][r]));
                tm = fmaxf(tm, __shfl_xor(tm, 1, 64));
                tm = fmaxf(tm, __shfl_xor(tm, 2, 64));
                tm = fmaxf(tm, __shfl_xor(tm, 4, 64));
                tm = fmaxf(tm, __shfl_xor(tm, 8, 64));
                const float mold  = mstate[r];
                const float mnew  = fmaxf(mold, tm);
                const float alpha = EXP2F(mold - mnew);
                float rsum = 0.0f;
#pragma unroll
                for (int n = 0; n < 4; ++n) {
                    float p = EXP2F(sv[n][r] - mnew);
                    rsum += p;
                    pW[(quad * 4 + r) * LDS_PS + n * 16 + l15] = (__bf16)p;
                }
                rsum += __shfl_xor(rsum, 1, 64);
                rsum += __shfl_xor(rsum, 2, 64);
                rsum += __shfl_xor(rsum, 4, 64);
                rsum += __shfl_xor(rsum, 8, 64);
                lstate[r] = lstate[r] * alpha + rsum;
                mstate[r] = mnew;
#pragma unroll
                for (int dt = 0; dt < 8; ++dt) oacc[dt][r] *= alpha;
            }
        }

        // ---- O += P V ----
#pragma unroll
        for (int kc2 = 0; kc2 < 2; ++kc2) {
            bf16x8_t af = *(const bf16x8_t*)&pW[l15 * LDS_PS + kc2 * 32 + quad * 8];
#pragma unroll
            for (int dt = 0; dt < 8; ++dt) {
                bf16x8_t bfr = *(const bf16x8_t*)&vT[(dt * 16 + l15) * LDS_VS + kc2 * 32 + quad * 8];
                oacc[dt] = __builtin_amdgcn_mfma_f32_16x16x32_bf16(af, bfr, oacc[dt], 0, 0, 0);
            }
        }
    }

    // ---- epilogue ----
#pragma unroll
    for (int r = 0; r < 4; ++r) {
        const float inv = 1.0f / lstate[r];
        const int srow = q0 + wave * 16 + quad * 4 + r;
        float* op = Og + (size_t)srow * ROW_STRIDE + head_off + l15;
#pragma unroll
        for (int dt = 0; dt < 8; ++dt) op[dt * 16] = oacc[dt][r] * inv;
    }
}

// ---------------- fallback (R2 kernel, fp32 in-kernel convert) ----------------

__global__ __launch_bounds__(256, 2) void fa_fallback(
    const float* __restrict__ Qg, const float* __restrict__ Kg,
    const float* __restrict__ Vg, const int* __restrict__ Mg,
    float* __restrict__ Og)
{
    __shared__ __bf16 kT[64 * 136];
    __shared__ __bf16 vT[DH * 68];
    __shared__ __bf16 pT[4 * 32 * 68];

    const int tid  = threadIdx.x;
    const int wave = tid >> 6;
    const int lane = tid & 63;
    const int l15  = lane & 15;
    const int quad = lane >> 4;

    const int bid = blockIdx.x;
    const int qt  = bid & 15;
    const int bh  = bid >> 4;
    const int h   = bh & (NH - 1);
    const int b   = bh >> 4;

    const int q0       = qt * 128;
    const int head_off = b * (NH * DH) + h * DH;

    const float kScale   = 1.44269504088896340736f / 11.31370849898476039f;
    const float kMaskVal = -14426.950408889634f;

    bf16x8_t qf[2][4];
#pragma unroll
    for (int mt = 0; mt < 2; ++mt) {
        const int srow = q0 + wave * 32 + mt * 16 + l15;
        const float* qp = Qg + (size_t)srow * ROW_STRIDE + head_off + quad * 8;
#pragma unroll
        for (int kc = 0; kc < 4; ++kc) {
            float4 f0 = *(const float4*)(qp + kc * 32);
            float4 f1 = *(const float4*)(qp + kc * 32 + 4);
            bf16x8_t v;
            v[0] = (__bf16)(f0.x * kScale); v[1] = (__bf16)(f0.y * kScale);
            v[2] = (__bf16)(f0.z * kScale); v[3] = (__bf16)(f0.w * kScale);
            v[4] = (__bf16)(f1.x * kScale); v[5] = (__bf16)(f1.y * kScale);
            v[6] = (__bf16)(f1.z * kScale); v[7] = (__bf16)(f1.w * kScale);
            qf[mt][kc] = v;
        }
    }

    f32x4_t oacc[2][8];
    float mstate[2][4], lstate[2][4];
#pragma unroll
    for (int mt = 0; mt < 2; ++mt) {
#pragma unroll
        for (int dt = 0; dt < 8; ++dt) oacc[mt][dt] = {0.0f, 0.0f, 0.0f, 0.0f};
#pragma unroll
        for (int r = 0; r < 4; ++r) { mstate[mt][r] = -3.0e38f; lstate[mt][r] = 0.0f; }
    }

    __bf16* pW = &pT[wave * 32 * 68];

    for (int kt = 0; kt < NKT; ++kt) {
        const int t0 = kt * N_TILE;
        __syncthreads();
        {
            const int r0 = tid >> 5;
            const int c4 = (tid & 31) * 4;
            const float* kp = Kg + (size_t)(t0 + r0) * ROW_STRIDE + head_off + c4;
            __bf16* kd = &kT[r0 * 136 + c4];
#pragma unroll
            for (int rr = 0; rr < 8; ++rr) {
                float4 f = *(const float4*)(kp + (size_t)rr * 8 * ROW_STRIDE);
                bf16x4_t w;
                w[0] = (__bf16)f.x; w[1] = (__bf16)f.y;
                w[2] = (__bf16)f.z; w[3] = (__bf16)f.w;
                *(bf16x4_t*)(kd + rr * 8 * 136) = w;
            }
        }
        {
            const int tv = tid >> 5;
            const int dv = tid & 31;
            const float* vp = Vg + (size_t)(t0 + tv) * ROW_STRIDE + head_off + dv;
#pragma unroll
            for (int rr = 0; rr < 8; ++rr) {
                const float* vpp = vp + (size_t)rr * 8 * ROW_STRIDE;
                const int trow = tv + rr * 8;
#pragma unroll
                for (int j = 0; j < 4; ++j)
                    vT[(dv + j * 32) * 68 + trow] = (__bf16)vpp[j * 32];
            }
        }
        __syncthreads();

        unsigned mpk = 0;
#pragma unroll
        for (int i = 0; i < 8; ++i) {
            const int mt = i >> 2, r = i & 3;
            const int row = q0 + wave * 32 + mt * 16 + quad * 4 + r;
            const int* mp = Mg + (size_t)b * S_LEN * S_LEN + (size_t)row * S_LEN + t0 + l15;
#pragma unroll
            for (int n = 0; n < 4; ++n)
                mpk |= (mp[n * 16] ? 1u : 0u) << (i * 4 + n);
        }

        f32x4_t sacc[2][4];
#pragma unroll
        for (int mt = 0; mt < 2; ++mt)
#pragma unroll
            for (int n = 0; n < 4; ++n) sacc[mt][n] = {0.0f, 0.0f, 0.0f, 0.0f};
#pragma unroll
        for (int n = 0; n < 4; ++n)
#pragma unroll
            for (int kc = 0; kc < 4; ++kc) {
                bf16x8_t kb = *(const bf16x8_t*)&kT[(n * 16 + l15) * 136 + kc * 32 + quad * 8];
                sacc[0][n] = __builtin_amdgcn_mfma_f32_16x16x32_bf16(qf[0][kc], kb, sacc[0][n], 0, 0, 0);
                sacc[1][n] = __builtin_amdgcn_mfma_f32_16x16x32_bf16(qf[1][kc], kb, sacc[1][n], 0, 0, 0);
            }

#pragma unroll
        for (int mt = 0; mt < 2; ++mt) {
            float sv[4][4];
#pragma unroll
            for (int n = 0; n < 4; ++n)
#pragma unroll
                for (int r = 0; r < 4; ++r)
                    sv[n][r] = ((mpk >> ((mt * 4 + r) * 4 + n)) & 1u) ? kMaskVal
                                                                      : sacc[mt][n][r];
#pragma unroll
            for (int r = 0; r < 4; ++r) {
                float tm = fmaxf(fmaxf(sv[0][r], sv[1][r]), fmaxf(sv[2][r], sv[3][r]));
                tm = fmaxf(tm, __shfl_xor(tm, 1, 64));
                tm = fmaxf(tm, __shfl_xor(tm, 2, 64));
                tm = fmaxf(tm, __shfl_xor(tm, 4, 64));
                tm = fmaxf(tm, __shfl_xor(tm, 8, 64));
                const float mold  = mstate[mt][r];
                const float mnew  = fmaxf(mold, tm);
                const float alpha = EXP2F(mold - mnew);
                float rsum = 0.0f;
#pragma unroll
                for (int n = 0; n < 4; ++n) {
                    float p = EXP2F(sv[n][r] - mnew);
                    rsum += p;
                    pW[(mt * 16 + quad * 4 + r) * 68 + n * 16 + l15] = (__bf16)p;
                }
                rsum += __shfl_xor(rsum, 1, 64);
                rsum += __shfl_xor(rsum, 2, 64);
                rsum += __shfl_xor(rsum, 4, 64);
                rsum += __shfl_xor(rsum, 8, 64);
                lstate[mt][r] = lstate[mt][r] * alpha + rsum;
                mstate[mt][r] = mnew;
#pragma unroll
                for (int dt = 0; dt < 8; ++dt) oacc[mt][dt][r] *= alpha;
            }
        }

#pragma unroll
        for (int kc2 = 0; kc2 < 2; ++kc2) {
            bf16x8_t af[2];
#pragma unroll
            for (int mt = 0; mt < 2; ++mt) {
                bf16x4_t lo = *(const bf16x4_t*)&pW[(mt * 16 + l15) * 68 + kc2 * 32 + quad * 8];
                bf16x4_t hi = *(const bf16x4_t*)&pW[(mt * 16 + l15) * 68 + kc2 * 32 + quad * 8 + 4];
                af[mt] = __builtin_shufflevector(lo, hi, 0, 1, 2, 3, 4, 5, 6, 7);
            }
#pragma unroll
            for (int dt = 0; dt < 8; ++dt) {
                bf16x4_t v0 = *(const bf16x4_t*)&vT[(dt * 16 + l15) * 68 + kc2 * 32 + quad * 8];
                bf16x4_t v1 = *(const bf16x4_t*)&vT[(dt * 16 + l15) * 68 + kc2 * 32 + quad * 8 + 4];
                bf16x8_t bfr = __builtin_shufflevector(v0, v1, 0, 1, 2, 3, 4, 5, 6, 7);
                oacc[0][dt] = __builtin_amdgcn_mfma_f32_16x16x32_bf16(af[0], bfr, oacc[0][dt], 0, 0, 0);
                oacc[1][dt] = __builtin_amdgcn_mfma_f32_16x16x32_bf16(af[1], bfr, oacc[1][dt], 0, 0, 0);
            }
        }
    }

#pragma unroll
    for (int mt = 0; mt < 2; ++mt)
#pragma unroll
        for (int r = 0; r < 4; ++r) {
            const float inv = 1.0f / lstate[mt][r];
            const int srow = q0 + wave * 32 + mt * 16 + quad * 4 + r;
            float* op = Og + (size_t)srow * ROW_STRIDE + head_off + l15;
#pragma unroll
            for (int dt = 0; dt < 8; ++dt) op[dt * 16] = oacc[mt][dt][r] * inv;
        }
}

extern "C" void kernel_launch(void* const* d_in, const int* in_sizes, int n_in,
                              void* d_out, int out_size, void* d_ws, size_t ws_size,
                              hipStream_t stream) {
    (void)in_sizes; (void)n_in; (void)out_size;
    const float* Q = (const float*)d_in[0];
    const float* K = (const float*)d_in[1];
    const float* V = (const float*)d_in[2];
    const int*   M = (const int*)d_in[3];
    float* O = (float*)d_out;
    dim3 block(256);
    if (d_ws != nullptr && ws_size >= WS_NEED) {
        char* ws = (char*)d_ws;
        __bf16* Kh = (__bf16*)(ws + WS_KH);
        __bf16* Vt = (__bf16*)(ws + WS_VT);
        unsigned long long* Mp = (unsigned long long*)(ws + WS_MP);
        hipLaunchKernelGGL(convert_k_kernel, dim3(4096), block, 0, stream, K, Kh);
        hipLaunchKernelGGL(transpose_v_kernel, dim3(1024), block, 0, stream, V, Vt);
        hipLaunchKernelGGL(mask_pack_kernel, dim3(512), block, 0, stream, M, Mp);
        hipLaunchKernelGGL(fa_main, dim3(NBH * 32), block, 0, stream,
                           Q, Kh, Vt, (const uint2*)Mp, O);
    } else {
        hipLaunchKernelGGL(fa_fallback, dim3(NBH * 16), block, 0, stream,
                           Q, K, V, M, O);
    }
}